// Round 3
// baseline (149.273 us; speedup 1.0000x reference)
//
#include <hip/hip_runtime.h>
#include <math.h>

typedef unsigned short u16;
typedef unsigned int   u32;
typedef __bf16 bf16x8 __attribute__((ext_vector_type(8)));
typedef float  f32x4  __attribute__((ext_vector_type(4)));
typedef u16    u16x8  __attribute__((ext_vector_type(8)));
typedef u16    u16x4  __attribute__((ext_vector_type(4)));

#define B_TOT 16384
#define DM_   1024
#define H_    256

// ---- workspace layout (bytes) ----
#define WS_SCORES 41943040   // proj bf16 [B][5][256] : 0 .. 41,943,040
#define WS_WP     42270720   // scores f32 [B][5]
#define WS_WA1    44367872   // Wp_mri bf16 [4][256][1024]
#define WS_WC1    44400640   // Wa1 bf16 [64][256]
#define WS_WC2    44466176   // Wc1 bf16 [128][256]; Wc2 bf16 [64][128] after

__device__ __forceinline__ u16 f2bf(float f){
  __bf16 h = (__bf16)f;
  return __builtin_bit_cast(u16, h);
}
__device__ __forceinline__ float bf2f(u16 h){
  return __builtin_bit_cast(float, ((u32)h) << 16);
}
__device__ __forceinline__ u16x4 cvt4(f32x4 a){
  u16x4 h;
  #pragma unroll
  for (int j = 0; j < 4; j++) h[j] = f2bf(a[j]);
  return h;
}
__device__ __forceinline__ f32x4 mfma16(bf16x8 a, bf16x8 b, f32x4 c){
  return __builtin_amdgcn_mfma_f32_16x16x32_bf16(a, b, c, 0, 0, 0);
}
// async global->LDS, 16B per lane; LDS dest = wave-uniform base + lane*16
__device__ __forceinline__ void glds16(const void* g, void* l){
  __builtin_amdgcn_global_load_lds(
      (const __attribute__((address_space(1))) void*)g,
      (__attribute__((address_space(3))) void*)l, 16, 0, 0);
}

// ---------------- K0: weight conversions to bf16 ----------------
__global__ void k0_convert(const float* __restrict__ s0, u16* __restrict__ d0, int n0,
                           const float* __restrict__ s1, u16* __restrict__ d1, int n1,
                           const float* __restrict__ s2, u16* __restrict__ d2, int n2,
                           const float* __restrict__ s3, u16* __restrict__ d3, int n3)
{
  int total4 = (n0 + n1 + n2 + n3) >> 2;
  for (int i = blockIdx.x * blockDim.x + threadIdx.x; i < total4; i += gridDim.x * blockDim.x){
    int e = i << 2;
    const float* s; u16* d; int off;
    if (e < n0)            { s = s0; d = d0; off = e; }
    else if (e < n0+n1)    { s = s1; d = d1; off = e - n0; }
    else if (e < n0+n1+n2) { s = s2; d = d2; off = e - n0 - n1; }
    else                   { s = s3; d = d3; off = e - n0 - n1 - n2; }
    f32x4 f = *(const f32x4*)(s + off);
    *(u16x4*)(d + off) = cvt4(f);
  }
}

// ---------------- K1b: clinical projection (K=8) + its attention score ----------------
__global__ __launch_bounds__(256) void k1b_clin(
    const float* __restrict__ fcl, const float* __restrict__ Wpcl, const float* __restrict__ bpcl,
    const u16* __restrict__ Wa1bf, const float* __restrict__ ba1,
    const float* __restrict__ Wa2, const float* __restrict__ ba2,
    u16* __restrict__ proj, float* __restrict__ scores)
{
  __shared__ u16 pcs[4][16*264];
  const int tid = threadIdx.x, lane = tid & 63, wv = tid >> 6;
  const int l15 = lane & 15, l4 = lane >> 4;
  const int rbase = blockIdx.x * 64 + wv * 16;

  f32x4 wA[4], wB[4];
  f32x4 bp = *(const f32x4*)(bpcl + lane * 4);
  #pragma unroll
  for (int c = 0; c < 4; c++){
    wA[c] = *(const f32x4*)(Wpcl + (lane*4 + c) * 8);
    wB[c] = *(const f32x4*)(Wpcl + (lane*4 + c) * 8 + 4);
  }
  #pragma unroll 4
  for (int r = 0; r < 16; r++){
    int row = rbase + r;
    f32x4 fA = *(const f32x4*)(fcl + (size_t)row * 8);
    f32x4 fB = *(const f32x4*)(fcl + (size_t)row * 8 + 4);
    u16x4 h;
    #pragma unroll
    for (int c = 0; c < 4; c++){
      float v = bp[c] + fA[0]*wA[c][0] + fA[1]*wA[c][1] + fA[2]*wA[c][2] + fA[3]*wA[c][3]
                      + fB[0]*wB[c][0] + fB[1]*wB[c][1] + fB[2]*wB[c][2] + fB[3]*wB[c][3];
      h[c] = f2bf(v);
    }
    *(u16x4*)(proj + (size_t)row * 1280 + 1024 + lane * 4) = h;
    *(u16x4*)(&pcs[wv][r * 264 + lane * 4]) = h;
  }
  f32x4 at[4];
  #pragma unroll
  for (int nf = 0; nf < 4; nf++) at[nf] = f32x4{0.f,0.f,0.f,0.f};
  #pragma unroll
  for (int kk = 0; kk < 8; kk++){
    bf16x8 a = *(const bf16x8*)((const char*)&pcs[wv][0] + l15*528 + kk*64 + l4*16);
    #pragma unroll
    for (int nf = 0; nf < 4; nf++){
      bf16x8 b = *(const bf16x8*)((const char*)Wa1bf + (nf*16 + l15)*512 + kk*64 + l4*16);
      at[nf] = mfma16(a, b, at[nf]);
    }
  }
  float po[4] = {0.f,0.f,0.f,0.f};
  #pragma unroll
  for (int nf = 0; nf < 4; nf++){
    int col = nf*16 + l15;
    float bb = ba1[col], w2 = Wa2[col];
    #pragma unroll
    for (int rg = 0; rg < 4; rg++) po[rg] += tanhf(at[nf][rg] + bb) * w2;
  }
  #pragma unroll
  for (int rg = 0; rg < 4; rg++){
    #pragma unroll
    for (int d = 1; d < 16; d <<= 1) po[rg] += __shfl_xor(po[rg], d);
  }
  if (l15 == 0){
    float b2 = ba2[0];
    #pragma unroll
    for (int rg = 0; rg < 4; rg++)
      scores[(size_t)(rbase + l4*4 + rg) * 5 + 4] = po[rg] + b2;
  }
}

// ---------------- K1: MRI projection GEMM + attention-MLP scores ----------------
// 1024 blocks (XCD-pair modality swizzle), 512 thr = 8 waves (2Mx4N of 32x64).
// BM=64, BN=256, BK=32. A staged as f32 via global_load_lds (convert at read);
// W bf16 via global_load_lds, 2 cols packed per 128B LDS row. Both XOR-swizzled
// through pre-swizzled SOURCE addresses (LDS dest stays linear).
// LDS 48KB: A dbuf 2x8KB @0, W dbuf 2x16KB @16384 -> 3 blocks/CU.
// One barrier per K-step (syncthreads drains vmcnt for the glds just issued).
__global__ __launch_bounds__(512, 6) void k1_proj(
    const float* __restrict__ ft1, const float* __restrict__ ft1c,
    const float* __restrict__ ft2, const float* __restrict__ ftfl,
    const u16* __restrict__ Wpbf, const float* __restrict__ bpm,
    const u16* __restrict__ Wa1bf, const float* __restrict__ ba1,
    const float* __restrict__ Wa2, const float* __restrict__ ba2,
    u16* __restrict__ proj, float* __restrict__ scores)
{
  extern __shared__ char lds[];
  const int bid = blockIdx.x;
  const int mm = (bid & 7) >> 1;                 // modality <- XCD pair
  const int bx = ((bid >> 3) << 1) | (bid & 1);  // 0..255 bijective
  const int b0 = bx * 64;
  const int tid = threadIdx.x;
  const int lane = tid & 63;
  const int wv = tid >> 6;
  const int wm = wv >> 2, wn = wv & 3;           // 2(M) x 4(N) waves, 32x64 tiles
  const int l15 = lane & 15, l4 = lane >> 4;

  const float* Am = (mm == 0) ? ft1 : ((mm == 1) ? ft1c : ((mm == 2) ? ft2 : ftfl));
  const char*  Wm = (const char*)(Wpbf + (size_t)mm * (H_ * DM_));
  const char*  Ab8 = (const char*)Am;

  // staging geometry (per thread, constant across iters)
  const int a_r = tid >> 3, a_c = tid & 7;                   // A: row, 16B chunk
  const size_t a_src0 = (size_t)(b0 + a_r) * 4096 + (size_t)((a_c*16) ^ ((a_r & 7) << 4));
  const int a_dstw = (tid >> 6) * 1024;                      // wave-uniform base (+lane*16)
  int w_pr[2], w_c[2]; size_t w_src0[2];
  #pragma unroll
  for (int i = 0; i < 2; i++){
    int q = i*512 + tid; w_pr[i] = q >> 3; w_c[i] = q & 7;
    int zp = (w_c[i]*16) ^ ((w_pr[i] & 7) << 4);
    int col = 2*w_pr[i] + (zp >> 6);
    w_src0[i] = (size_t)col * 2048 + (size_t)(zp & 63);
  }

  f32x4 acc[2][4];
  #pragma unroll
  for (int i = 0; i < 2; i++)
    #pragma unroll
    for (int j = 0; j < 4; j++) acc[i][j] = f32x4{0.f,0.f,0.f,0.f};

  // fragment-read geometry
  int a_off[2], w_off[4];
  #pragma unroll
  for (int mf = 0; mf < 2; mf++){
    int r = wm*32 + mf*16 + l15;
    a_off[mf] = r*128 + ((l4*32) ^ ((r & 7) << 4));
  }
  int a_off2[2];
  #pragma unroll
  for (int mf = 0; mf < 2; mf++){
    int r = wm*32 + mf*16 + l15;
    a_off2[mf] = r*128 + (((l4*32) + 16) ^ ((r & 7) << 4));
  }
  #pragma unroll
  for (int nf = 0; nf < 4; nf++){
    int col = wn*64 + nf*16 + l15;
    int p = col >> 1, qq = col & 1;
    w_off[nf] = p*128 + (((qq*64) + l4*16) ^ ((p & 7) << 4));
  }

  // prologue: stage k-tile 0 into buf 0
  glds16(Ab8 + a_src0, lds + a_dstw);
  #pragma unroll
  for (int i = 0; i < 2; i++)
    glds16(Wm + w_src0[i], lds + 16384 + i*8192 + a_dstw);
  __syncthreads();

  for (int kt = 0; kt < 32; ++kt){
    const int cur = kt & 1;
    if (kt < 31){  // issue next-tile async loads first (overlap with compute)
      const int nb = cur ^ 1;
      glds16(Ab8 + a_src0 + (size_t)(kt+1)*128, lds + nb*8192 + a_dstw);
      #pragma unroll
      for (int i = 0; i < 2; i++)
        glds16(Wm + w_src0[i] + (size_t)(kt+1)*64, lds + 16384 + nb*16384 + i*8192 + a_dstw);
    }
    const char* Abuf = lds + cur*8192;
    const char* Wbuf = lds + 16384 + cur*16384;
    bf16x8 af[2];
    #pragma unroll
    for (int mf = 0; mf < 2; mf++){
      f32x4 a0 = *(const f32x4*)(Abuf + a_off[mf]);
      f32x4 a1 = *(const f32x4*)(Abuf + a_off2[mf]);
      bf16x8 h;
      #pragma unroll
      for (int j = 0; j < 4; j++){ h[j] = (__bf16)a0[j]; h[4+j] = (__bf16)a1[j]; }
      af[mf] = h;
    }
    #pragma unroll
    for (int nf = 0; nf < 4; nf++){
      bf16x8 wfr = *(const bf16x8*)(Wbuf + w_off[nf]);
      #pragma unroll
      for (int mf = 0; mf < 2; mf++)
        acc[mf][nf] = mfma16(af[mf], wfr, acc[mf][nf]);
    }
    __syncthreads();   // drains glds (vmcnt) + lgkm, releases both buffers
  }

  // epilogue: acc(+bias) -> lds proj tile [64][512B] swizzled (overlays buffers)
  {
    float bias[4];
    #pragma unroll
    for (int nf = 0; nf < 4; nf++) bias[nf] = bpm[mm*256 + wn*64 + nf*16 + l15];
    #pragma unroll
    for (int mf = 0; mf < 2; mf++){
      #pragma unroll
      for (int nf = 0; nf < 4; nf++){
        int cc = wn*64 + nf*16 + l15;
        #pragma unroll
        for (int rg = 0; rg < 4; rg++){
          int r = wm*32 + mf*16 + l4*4 + rg;
          *(u16*)(lds + r*512 + ((cc*2) ^ ((r & 7) << 4))) = f2bf(acc[mf][nf][rg] + bias[nf]);
        }
      }
    }
  }
  __syncthreads();

  // proj tile -> global (64 rows x 512B)
  #pragma unroll
  for (int i = 0; i < 4; i++){
    int q = i*512 + tid;
    int r = q >> 5, c = q & 31;
    u16x8 v = *(const u16x8*)(lds + r*512 + ((c*16) ^ ((r & 7) << 4)));
    *(u16x8*)((char*)proj + (size_t)(b0 + r) * 2560 + mm*512 + c*16) = v;
  }
  // attention MLP: waves 0..3 own rows [wv*16, wv*16+16)
  if (wv < 4){
    f32x4 a2[4];
    #pragma unroll
    for (int nf = 0; nf < 4; nf++) a2[nf] = f32x4{0.f,0.f,0.f,0.f};
    #pragma unroll
    for (int kk = 0; kk < 8; kk++){
      int kb = kk*64 + l4*16;
      int r = wv*16 + l15;
      bf16x8 afr = *(const bf16x8*)(lds + r*512 + (kb ^ ((r & 7) << 4)));
      #pragma unroll
      for (int nf = 0; nf < 4; nf++){
        int n = nf*16 + l15;
        bf16x8 bfr = *(const bf16x8*)((const char*)Wa1bf + n*512 + kb);
        a2[nf] = mfma16(afr, bfr, a2[nf]);
      }
    }
    float p0 = 0.f, p1 = 0.f, p2 = 0.f, p3 = 0.f;
    #pragma unroll
    for (int nf = 0; nf < 4; nf++){
      int n = nf*16 + l15;
      float w2 = Wa2[n], bn = ba1[n];
      p0 += tanhf(a2[nf][0] + bn) * w2;
      p1 += tanhf(a2[nf][1] + bn) * w2;
      p2 += tanhf(a2[nf][2] + bn) * w2;
      p3 += tanhf(a2[nf][3] + bn) * w2;
    }
    #pragma unroll
    for (int d = 1; d < 16; d <<= 1){
      p0 += __shfl_xor(p0, d); p1 += __shfl_xor(p1, d);
      p2 += __shfl_xor(p2, d); p3 += __shfl_xor(p3, d);
    }
    if (l15 == 0){
      float bav = ba2[0];
      int rb = wv*16 + l4*4;
      scores[(size_t)(b0 + rb + 0)*5 + mm] = p0 + bav;
      scores[(size_t)(b0 + rb + 1)*5 + mm] = p1 + bav;
      scores[(size_t)(b0 + rb + 2)*5 + mm] = p2 + bav;
      scores[(size_t)(b0 + rb + 3)*5 + mm] = p3 + bav;
    }
  }
}

// ---------------- K2: softmax + fuse + MFMA classifier ----------------
__global__ __launch_bounds__(256) void k2_cls(
    const u16* __restrict__ proj, const float* __restrict__ scores,
    const u16* __restrict__ Wc1bf, const u16* __restrict__ Wc2bf,
    const float* __restrict__ bc1, const float* __restrict__ g1, const float* __restrict__ be1,
    const float* __restrict__ bc2, const float* __restrict__ g2, const float* __restrict__ be2,
    const float* __restrict__ Wc3, const float* __restrict__ bc3,
    float* __restrict__ outp)
{
  __shared__ u16 h1s[4][16*136];
  const int tid = threadIdx.x, lane = tid & 63, wv = tid >> 6;
  const int l15 = lane & 15, l4 = lane >> 4;
  const int b0 = blockIdx.x * 64;
  const int rowA = b0 + wv*16 + l15;

  const float* sc = scores + (size_t)rowA * 5;
  float s0 = sc[0], s1 = sc[1], s2 = sc[2], s3 = sc[3], s4 = sc[4];
  float mx = fmaxf(fmaxf(fmaxf(s0, s1), fmaxf(s2, s3)), s4);
  float e0 = expf(s0-mx), e1 = expf(s1-mx), e2 = expf(s2-mx), e3 = expf(s3-mx), e4 = expf(s4-mx);
  float inv = 1.0f / (e0 + e1 + e2 + e3 + e4);
  float w0 = e0*inv, w1 = e1*inv, w2 = e2*inv, w3 = e3*inv, w4 = e4*inv;
  if (l4 == 0){
    float* ap = outp + B_TOT + (size_t)rowA * 5;
    ap[0] = w0; ap[1] = w1; ap[2] = w2; ap[3] = w3; ap[4] = w4;
  }

  bf16x8 af[8];
  const u16* pr = proj + (size_t)rowA * 1280 + l4*8;
  #pragma unroll
  for (int kk = 0; kk < 8; kk++){
    u16x8 p0v = *(const u16x8*)(pr + kk*32);
    u16x8 p1v = *(const u16x8*)(pr + 256  + kk*32);
    u16x8 p2v = *(const u16x8*)(pr + 512  + kk*32);
    u16x8 p3v = *(const u16x8*)(pr + 768  + kk*32);
    u16x8 p4v = *(const u16x8*)(pr + 1024 + kk*32);
    bf16x8 a;
    #pragma unroll
    for (int j = 0; j < 8; j++)
      a[j] = (__bf16)(w0*bf2f(p0v[j]) + w1*bf2f(p1v[j]) + w2*bf2f(p2v[j])
                    + w3*bf2f(p3v[j]) + w4*bf2f(p4v[j]));
    af[kk] = a;
  }

  f32x4 acc1[8];
  #pragma unroll
  for (int of = 0; of < 8; of++) acc1[of] = f32x4{0.f,0.f,0.f,0.f};
  #pragma unroll
  for (int kk = 0; kk < 8; kk++){
    #pragma unroll
    for (int of = 0; of < 8; of++){
      bf16x8 b = *(const bf16x8*)((const char*)Wc1bf + (of*16 + l15)*512 + kk*64 + l4*16);
      acc1[of] = mfma16(af[kk], b, acc1[of]);
    }
  }
  float sum1[4] = {0.f,0.f,0.f,0.f};
  #pragma unroll
  for (int of = 0; of < 8; of++){
    float bb = bc1[of*16 + l15];
    #pragma unroll
    for (int rg = 0; rg < 4; rg++){ acc1[of][rg] += bb; sum1[rg] += acc1[of][rg]; }
  }
  #pragma unroll
  for (int rg = 0; rg < 4; rg++){
    #pragma unroll
    for (int d = 1; d < 16; d <<= 1) sum1[rg] += __shfl_xor(sum1[rg], d);
  }
  float vs1[4] = {0.f,0.f,0.f,0.f};
  float mean1[4];
  #pragma unroll
  for (int rg = 0; rg < 4; rg++) mean1[rg] = sum1[rg] * 0.0078125f;
  #pragma unroll
  for (int of = 0; of < 8; of++)
    #pragma unroll
    for (int rg = 0; rg < 4; rg++){ float dd = acc1[of][rg] - mean1[rg]; vs1[rg] += dd*dd; }
  #pragma unroll
  for (int rg = 0; rg < 4; rg++){
    #pragma unroll
    for (int d = 1; d < 16; d <<= 1) vs1[rg] += __shfl_xor(vs1[rg], d);
  }
  float is1[4];
  #pragma unroll
  for (int rg = 0; rg < 4; rg++) is1[rg] = rsqrtf(vs1[rg] * 0.0078125f + 1e-5f);
  #pragma unroll
  for (int of = 0; of < 8; of++){
    int col = of*16 + l15;
    float gg = g1[col], bb = be1[col];
    #pragma unroll
    for (int rg = 0; rg < 4; rg++){
      float h = fmaxf((acc1[of][rg] - mean1[rg]) * is1[rg] * gg + bb, 0.f);
      h1s[wv][(l4*4 + rg)*136 + col] = f2bf(h);
    }
  }

  f32x4 acc2[4];
  #pragma unroll
  for (int of = 0; of < 4; of++) acc2[of] = f32x4{0.f,0.f,0.f,0.f};
  #pragma unroll
  for (int kk = 0; kk < 4; kk++){
    bf16x8 a2 = *(const bf16x8*)((const char*)&h1s[wv][0] + l15*272 + kk*64 + l4*16);
    #pragma unroll
    for (int of = 0; of < 4; of++){
      bf16x8 b = *(const bf16x8*)((const char*)Wc2bf + (of*16 + l15)*256 + kk*64 + l4*16);
      acc2[of] = mfma16(a2, b, acc2[of]);
    }
  }
  float sum2[4] = {0.f,0.f,0.f,0.f};
  #pragma unroll
  for (int of = 0; of < 4; of++){
    float bb = bc2[of*16 + l15];
    #pragma unroll
    for (int rg = 0; rg < 4; rg++){ acc2[of][rg] += bb; sum2[rg] += acc2[of][rg]; }
  }
  #pragma unroll
  for (int rg = 0; rg < 4; rg++){
    #pragma unroll
    for (int d = 1; d < 16; d <<= 1) sum2[rg] += __shfl_xor(sum2[rg], d);
  }
  float mean2[4], vs2[4] = {0.f,0.f,0.f,0.f};
  #pragma unroll
  for (int rg = 0; rg < 4; rg++) mean2[rg] = sum2[rg] * 0.015625f;
  #pragma unroll
  for (int of = 0; of < 4; of++)
    #pragma unroll
    for (int rg = 0; rg < 4; rg++){ float dd = acc2[of][rg] - mean2[rg]; vs2[rg] += dd*dd; }
  #pragma unroll
  for (int rg = 0; rg < 4; rg++){
    #pragma unroll
    for (int d = 1; d < 16; d <<= 1) vs2[rg] += __shfl_xor(vs2[rg], d);
  }
  float po[4] = {0.f,0.f,0.f,0.f};
  #pragma unroll
  for (int of = 0; of < 4; of++){
    int col = of*16 + l15;
    float gg = g2[col], bb = be2[col], w3c = Wc3[col];
    #pragma unroll
    for (int rg = 0; rg < 4; rg++){
      float is2 = rsqrtf(vs2[rg] * 0.015625f + 1e-5f);
      float h = fmaxf((acc2[of][rg] - mean2[rg]) * is2 * gg + bb, 0.f);
      po[rg] += h * w3c;
    }
  }
  #pragma unroll
  for (int rg = 0; rg < 4; rg++){
    #pragma unroll
    for (int d = 1; d < 16; d <<= 1) po[rg] += __shfl_xor(po[rg], d);
  }
  if (l15 == 0){
    float b3 = bc3[0];
    #pragma unroll
    for (int rg = 0; rg < 4; rg++)
      outp[b0 + wv*16 + l4*4 + rg] = po[rg] + b3;
  }
}

extern "C" void kernel_launch(void* const* d_in, const int* in_sizes, int n_in,
                              void* d_out, int out_size, void* d_ws, size_t ws_size,
                              hipStream_t stream)
{
  (void)in_sizes; (void)n_in; (void)out_size; (void)ws_size;
  const float* ft1  = (const float*)d_in[0];
  const float* ft1c = (const float*)d_in[1];
  const float* ft2  = (const float*)d_in[2];
  const float* ftfl = (const float*)d_in[3];
  const float* fcl  = (const float*)d_in[4];
  const float* Wpmri= (const float*)d_in[5];
  const float* bpm  = (const float*)d_in[6];
  const float* Wpcl = (const float*)d_in[7];
  const float* bpcl = (const float*)d_in[8];
  const float* Wa1  = (const float*)d_in[9];
  const float* ba1  = (const float*)d_in[10];
  const float* Wa2  = (const float*)d_in[11];
  const float* ba2  = (const float*)d_in[12];
  const float* Wc1  = (const float*)d_in[13];
  const float* bc1  = (const float*)d_in[14];
  const float* g1   = (const float*)d_in[15];
  const float* be1  = (const float*)d_in[16];
  const float* Wc2  = (const float*)d_in[17];
  const float* bc2  = (const float*)d_in[18];
  const float* g2   = (const float*)d_in[19];
  const float* be2  = (const float*)d_in[20];
  const float* Wc3  = (const float*)d_in[21];
  const float* bc3  = (const float*)d_in[22];
  float* outp = (float*)d_out;
  char* ws = (char*)d_ws;

  u16*   proj   = (u16*)(ws);
  float* scores = (float*)(ws + WS_SCORES);
  u16*   Wpbf   = (u16*)(ws + WS_WP);
  u16*   Wa1bf  = (u16*)(ws + WS_WA1);
  u16*   Wc1bf  = (u16*)(ws + WS_WC1);
  u16*   Wc2bf  = (u16*)(ws + WS_WC2);

  k0_convert<<<dim3(512), dim3(256), 0, stream>>>(
      Wpmri, Wpbf, 4 * H_ * DM_,
      Wa1,  Wa1bf, 64 * H_,
      Wc1,  Wc1bf, 128 * H_,
      Wc2,  Wc2bf, 64 * 128);

  k1b_clin<<<dim3(256), dim3(256), 0, stream>>>(
      fcl, Wpcl, bpcl, Wa1bf, ba1, Wa2, ba2, proj, scores);

  k1_proj<<<dim3(1024), dim3(512), 49152, stream>>>(
      ft1, ft1c, ft2, ftfl, Wpbf, bpm, Wa1bf, ba1, Wa2, ba2, proj, scores);

  k2_cls<<<dim3(256), dim3(256), 0, stream>>>(
      proj, scores, Wc1bf, Wc2bf, bc1, g1, be1, bc2, g2, be2, Wc3, bc3, outp);
}

// Round 4
// 141.567 us; speedup vs baseline: 1.0544x; 1.0544x over previous
//
#include <hip/hip_runtime.h>
#include <math.h>

typedef unsigned short u16;
typedef unsigned int   u32;
typedef __bf16 bf16x8 __attribute__((ext_vector_type(8)));
typedef float  f32x4  __attribute__((ext_vector_type(4)));
typedef u16    u16x8  __attribute__((ext_vector_type(8)));
typedef u16    u16x4  __attribute__((ext_vector_type(4)));

#define B_TOT 16384
#define DM_   1024
#define H_    256

// ---- workspace layout (bytes) ----
#define WS_SCORES 41943040   // proj bf16 [B][5][256] : 0 .. 41,943,040
#define WS_WP     42270720   // scores f32 [B][5]
#define WS_WA1    44367872   // Wp_mri bf16 [4][256][1024]
#define WS_WC1    44400640   // Wa1 bf16 [64][256]
#define WS_WC2    44466176   // Wc1 bf16 [128][256]; Wc2 bf16 [64][128] after

__device__ __forceinline__ u16 f2bf(float f){
  __bf16 h = (__bf16)f;
  return __builtin_bit_cast(u16, h);
}
__device__ __forceinline__ float bf2f(u16 h){
  return __builtin_bit_cast(float, ((u32)h) << 16);
}
__device__ __forceinline__ u16x4 cvt4(f32x4 a){
  u16x4 h;
  #pragma unroll
  for (int j = 0; j < 4; j++) h[j] = f2bf(a[j]);
  return h;
}
__device__ __forceinline__ f32x4 mfma16(bf16x8 a, bf16x8 b, f32x4 c){
  return __builtin_amdgcn_mfma_f32_16x16x32_bf16(a, b, c, 0, 0, 0);
}
// async global->LDS, 16B per lane; LDS dest = wave-uniform base + lane*16
__device__ __forceinline__ void glds16(const void* g, void* l){
  __builtin_amdgcn_global_load_lds(
      (const __attribute__((address_space(1))) void*)g,
      (__attribute__((address_space(3))) void*)l, 16, 0, 0);
}

// ---------------- K0: weight conversions to bf16 ----------------
__global__ void k0_convert(const float* __restrict__ s0, u16* __restrict__ d0, int n0,
                           const float* __restrict__ s1, u16* __restrict__ d1, int n1,
                           const float* __restrict__ s2, u16* __restrict__ d2, int n2,
                           const float* __restrict__ s3, u16* __restrict__ d3, int n3)
{
  int total4 = (n0 + n1 + n2 + n3) >> 2;
  for (int i = blockIdx.x * blockDim.x + threadIdx.x; i < total4; i += gridDim.x * blockDim.x){
    int e = i << 2;
    const float* s; u16* d; int off;
    if (e < n0)            { s = s0; d = d0; off = e; }
    else if (e < n0+n1)    { s = s1; d = d1; off = e - n0; }
    else if (e < n0+n1+n2) { s = s2; d = d2; off = e - n0 - n1; }
    else                   { s = s3; d = d3; off = e - n0 - n1 - n2; }
    f32x4 f = *(const f32x4*)(s + off);
    *(u16x4*)(d + off) = cvt4(f);
  }
}

// ---------------- K1b: clinical projection (K=8) + its attention score ----------------
__global__ __launch_bounds__(256) void k1b_clin(
    const float* __restrict__ fcl, const float* __restrict__ Wpcl, const float* __restrict__ bpcl,
    const u16* __restrict__ Wa1bf, const float* __restrict__ ba1,
    const float* __restrict__ Wa2, const float* __restrict__ ba2,
    u16* __restrict__ proj, float* __restrict__ scores)
{
  __shared__ u16 pcs[4][16*264];
  const int tid = threadIdx.x, lane = tid & 63, wv = tid >> 6;
  const int l15 = lane & 15, l4 = lane >> 4;
  const int rbase = blockIdx.x * 64 + wv * 16;

  f32x4 wA[4], wB[4];
  f32x4 bp = *(const f32x4*)(bpcl + lane * 4);
  #pragma unroll
  for (int c = 0; c < 4; c++){
    wA[c] = *(const f32x4*)(Wpcl + (lane*4 + c) * 8);
    wB[c] = *(const f32x4*)(Wpcl + (lane*4 + c) * 8 + 4);
  }
  #pragma unroll 4
  for (int r = 0; r < 16; r++){
    int row = rbase + r;
    f32x4 fA = *(const f32x4*)(fcl + (size_t)row * 8);
    f32x4 fB = *(const f32x4*)(fcl + (size_t)row * 8 + 4);
    u16x4 h;
    #pragma unroll
    for (int c = 0; c < 4; c++){
      float v = bp[c] + fA[0]*wA[c][0] + fA[1]*wA[c][1] + fA[2]*wA[c][2] + fA[3]*wA[c][3]
                      + fB[0]*wB[c][0] + fB[1]*wB[c][1] + fB[2]*wB[c][2] + fB[3]*wB[c][3];
      h[c] = f2bf(v);
    }
    *(u16x4*)(proj + (size_t)row * 1280 + 1024 + lane * 4) = h;
    *(u16x4*)(&pcs[wv][r * 264 + lane * 4]) = h;
  }
  f32x4 at[4];
  #pragma unroll
  for (int nf = 0; nf < 4; nf++) at[nf] = f32x4{0.f,0.f,0.f,0.f};
  #pragma unroll
  for (int kk = 0; kk < 8; kk++){
    bf16x8 a = *(const bf16x8*)((const char*)&pcs[wv][0] + l15*528 + kk*64 + l4*16);
    #pragma unroll
    for (int nf = 0; nf < 4; nf++){
      bf16x8 b = *(const bf16x8*)((const char*)Wa1bf + (nf*16 + l15)*512 + kk*64 + l4*16);
      at[nf] = mfma16(a, b, at[nf]);
    }
  }
  float po[4] = {0.f,0.f,0.f,0.f};
  #pragma unroll
  for (int nf = 0; nf < 4; nf++){
    int col = nf*16 + l15;
    float bb = ba1[col], w2 = Wa2[col];
    #pragma unroll
    for (int rg = 0; rg < 4; rg++) po[rg] += tanhf(at[nf][rg] + bb) * w2;
  }
  #pragma unroll
  for (int rg = 0; rg < 4; rg++){
    #pragma unroll
    for (int d = 1; d < 16; d <<= 1) po[rg] += __shfl_xor(po[rg], d);
  }
  if (l15 == 0){
    float b2 = ba2[0];
    #pragma unroll
    for (int rg = 0; rg < 4; rg++)
      scores[(size_t)(rbase + l4*4 + rg) * 5 + 4] = po[rg] + b2;
  }
}

// ---------------- K1: MRI projection GEMM + attention-MLP scores ----------------
// 1024 blocks (XCD-pair modality swizzle), 512 thr = 8 waves (2Mx4N of 32x64).
// BM=64, BN=256, BK=32. Triple-buffered ring, depth-2 glds prefetch, counted
// vmcnt (never 0 in-loop). LDS 72KB: A f32 3x8KB @0, W bf16 3x16KB @24576.
// Epilogue overlays proj tile [64][512B] @0.
__global__ __launch_bounds__(512, 4) void k1_proj(
    const float* __restrict__ ft1, const float* __restrict__ ft1c,
    const float* __restrict__ ft2, const float* __restrict__ ftfl,
    const u16* __restrict__ Wpbf, const float* __restrict__ bpm,
    const u16* __restrict__ Wa1bf, const float* __restrict__ ba1,
    const float* __restrict__ Wa2, const float* __restrict__ ba2,
    u16* __restrict__ proj, float* __restrict__ scores)
{
  extern __shared__ char lds[];
  const int bid = blockIdx.x;
  const int mm = (bid & 7) >> 1;                 // modality <- XCD pair
  const int bx = ((bid >> 3) << 1) | (bid & 1);  // 0..255 bijective
  const int b0 = bx * 64;
  const int tid = threadIdx.x;
  const int lane = tid & 63;
  const int wv = tid >> 6;
  const int wm = wv >> 2, wn = wv & 3;           // 2(M) x 4(N) waves, 32x64 tiles
  const int l15 = lane & 15, l4 = lane >> 4;

  const float* Am = (mm == 0) ? ft1 : ((mm == 1) ? ft1c : ((mm == 2) ? ft2 : ftfl));
  const char*  Wm = (const char*)(Wpbf + (size_t)mm * (H_ * DM_));
  const char*  Ab8 = (const char*)Am;

  // staging geometry (per thread, constant across iters)
  const int a_r = tid >> 3, a_c = tid & 7;                   // A: row, 16B chunk
  const size_t a_src0 = (size_t)(b0 + a_r) * 4096 + (size_t)((a_c*16) ^ ((a_r & 7) << 4));
  const int a_dstw = (tid >> 6) * 1024;                      // wave-uniform base (+lane*16)
  size_t w_src0[2];
  #pragma unroll
  for (int i = 0; i < 2; i++){
    int q = i*512 + tid; int pr = q >> 3, c = q & 7;
    int zp = (c*16) ^ ((pr & 7) << 4);
    int col = 2*pr + (zp >> 6);
    w_src0[i] = (size_t)col * 2048 + (size_t)(zp & 63);
  }

  f32x4 acc[2][4];
  #pragma unroll
  for (int i = 0; i < 2; i++)
    #pragma unroll
    for (int j = 0; j < 4; j++) acc[i][j] = f32x4{0.f,0.f,0.f,0.f};

  // fragment-read geometry
  int a_off[2], a_off2[2], w_off[4];
  #pragma unroll
  for (int mf = 0; mf < 2; mf++){
    int r = wm*32 + mf*16 + l15;
    a_off[mf]  = r*128 + ((l4*32) ^ ((r & 7) << 4));
    a_off2[mf] = r*128 + (((l4*32) + 16) ^ ((r & 7) << 4));
  }
  #pragma unroll
  for (int nf = 0; nf < 4; nf++){
    int col = wn*64 + nf*16 + l15;
    int p = col >> 1, qq = col & 1;
    w_off[nf] = p*128 + (((qq*64) + l4*16) ^ ((p & 7) << 4));
  }

  // stage tile t into ring buffer t%3 (3 glds per thread: 1 A + 2 W)
  auto stage = [&](int t){
    int bc = t % 3;
    glds16(Ab8 + a_src0 + (size_t)t * 128, lds + bc*8192 + a_dstw);
    #pragma unroll
    for (int i = 0; i < 2; i++)
      glds16(Wm + w_src0[i] + (size_t)t * 64, lds + 24576 + bc*16384 + i*8192 + a_dstw);
  };
  auto compute = [&](int t){
    int bc = t % 3;
    const char* Abuf = lds + bc*8192;
    const char* Wbuf = lds + 24576 + bc*16384;
    bf16x8 af[2];
    #pragma unroll
    for (int mf = 0; mf < 2; mf++){
      f32x4 a0 = *(const f32x4*)(Abuf + a_off[mf]);
      f32x4 a1 = *(const f32x4*)(Abuf + a_off2[mf]);
      bf16x8 h;
      #pragma unroll
      for (int j = 0; j < 4; j++){ h[j] = (__bf16)a0[j]; h[4+j] = (__bf16)a1[j]; }
      af[mf] = h;
    }
    bf16x8 wfr[4];
    #pragma unroll
    for (int nf = 0; nf < 4; nf++) wfr[nf] = *(const bf16x8*)(Wbuf + w_off[nf]);
    __builtin_amdgcn_s_setprio(1);
    #pragma unroll
    for (int nf = 0; nf < 4; nf++){
      #pragma unroll
      for (int mf = 0; mf < 2; mf++)
        acc[mf][nf] = mfma16(af[mf], wfr[nf], acc[mf][nf]);
    }
    __builtin_amdgcn_s_setprio(0);
  };

  // prologue: stage tiles 0 and 1
  stage(0);
  stage(1);

  // main loop: iters 0..30 with counted vmcnt(3); peel iter 31 with vmcnt(0)
  for (int kt = 0; kt < 31; ++kt){
    asm volatile("s_waitcnt vmcnt(3)" ::: "memory");  // tile kt landed (kt+1 in flight)
    __builtin_amdgcn_s_barrier();                     // all waves' portions landed
    __builtin_amdgcn_sched_barrier(0);                // no motion across the barrier
    if (kt + 2 < 32) stage(kt + 2);                   // overwrites buf of tile kt-1 (retired)
    compute(kt);
  }
  asm volatile("s_waitcnt vmcnt(0)" ::: "memory");
  __builtin_amdgcn_s_barrier();
  __builtin_amdgcn_sched_barrier(0);
  compute(31);

  __syncthreads();   // everyone done with ring buffers before overlay

  // epilogue: acc(+bias) -> lds proj tile [64][512B] swizzled (overlays buffers)
  {
    float bias[4];
    #pragma unroll
    for (int nf = 0; nf < 4; nf++) bias[nf] = bpm[mm*256 + wn*64 + nf*16 + l15];
    #pragma unroll
    for (int mf = 0; mf < 2; mf++){
      #pragma unroll
      for (int nf = 0; nf < 4; nf++){
        int cc = wn*64 + nf*16 + l15;
        #pragma unroll
        for (int rg = 0; rg < 4; rg++){
          int r = wm*32 + mf*16 + l4*4 + rg;
          *(u16*)(lds + r*512 + ((cc*2) ^ ((r & 7) << 4))) = f2bf(acc[mf][nf][rg] + bias[nf]);
        }
      }
    }
  }
  __syncthreads();

  // proj tile -> global (64 rows x 512B)
  #pragma unroll
  for (int i = 0; i < 4; i++){
    int q = i*512 + tid;
    int r = q >> 5, c = q & 31;
    u16x8 v = *(const u16x8*)(lds + r*512 + ((c*16) ^ ((r & 7) << 4)));
    *(u16x8*)((char*)proj + (size_t)(b0 + r) * 2560 + mm*512 + c*16) = v;
  }
  // attention MLP: waves 0..3 own rows [wv*16, wv*16+16)
  if (wv < 4){
    f32x4 a2[4];
    #pragma unroll
    for (int nf = 0; nf < 4; nf++) a2[nf] = f32x4{0.f,0.f,0.f,0.f};
    #pragma unroll
    for (int kk = 0; kk < 8; kk++){
      int kb = kk*64 + l4*16;
      int r = wv*16 + l15;
      bf16x8 afr = *(const bf16x8*)(lds + r*512 + (kb ^ ((r & 7) << 4)));
      #pragma unroll
      for (int nf = 0; nf < 4; nf++){
        int n = nf*16 + l15;
        bf16x8 bfr = *(const bf16x8*)((const char*)Wa1bf + n*512 + kb);
        a2[nf] = mfma16(afr, bfr, a2[nf]);
      }
    }
    float p0 = 0.f, p1 = 0.f, p2 = 0.f, p3 = 0.f;
    #pragma unroll
    for (int nf = 0; nf < 4; nf++){
      int n = nf*16 + l15;
      float w2 = Wa2[n], bn = ba1[n];
      p0 += tanhf(a2[nf][0] + bn) * w2;
      p1 += tanhf(a2[nf][1] + bn) * w2;
      p2 += tanhf(a2[nf][2] + bn) * w2;
      p3 += tanhf(a2[nf][3] + bn) * w2;
    }
    #pragma unroll
    for (int d = 1; d < 16; d <<= 1){
      p0 += __shfl_xor(p0, d); p1 += __shfl_xor(p1, d);
      p2 += __shfl_xor(p2, d); p3 += __shfl_xor(p3, d);
    }
    if (l15 == 0){
      float bav = ba2[0];
      int rb = wv*16 + l4*4;
      scores[(size_t)(b0 + rb + 0)*5 + mm] = p0 + bav;
      scores[(size_t)(b0 + rb + 1)*5 + mm] = p1 + bav;
      scores[(size_t)(b0 + rb + 2)*5 + mm] = p2 + bav;
      scores[(size_t)(b0 + rb + 3)*5 + mm] = p3 + bav;
    }
  }
}

// ---------------- K2: softmax + fuse + MFMA classifier ----------------
__global__ __launch_bounds__(256) void k2_cls(
    const u16* __restrict__ proj, const float* __restrict__ scores,
    const u16* __restrict__ Wc1bf, const u16* __restrict__ Wc2bf,
    const float* __restrict__ bc1, const float* __restrict__ g1, const float* __restrict__ be1,
    const float* __restrict__ bc2, const float* __restrict__ g2, const float* __restrict__ be2,
    const float* __restrict__ Wc3, const float* __restrict__ bc3,
    float* __restrict__ outp)
{
  __shared__ u16 h1s[4][16*136];
  const int tid = threadIdx.x, lane = tid & 63, wv = tid >> 6;
  const int l15 = lane & 15, l4 = lane >> 4;
  const int b0 = blockIdx.x * 64;
  const int rowA = b0 + wv*16 + l15;

  const float* sc = scores + (size_t)rowA * 5;
  float s0 = sc[0], s1 = sc[1], s2 = sc[2], s3 = sc[3], s4 = sc[4];
  float mx = fmaxf(fmaxf(fmaxf(s0, s1), fmaxf(s2, s3)), s4);
  float e0 = expf(s0-mx), e1 = expf(s1-mx), e2 = expf(s2-mx), e3 = expf(s3-mx), e4 = expf(s4-mx);
  float inv = 1.0f / (e0 + e1 + e2 + e3 + e4);
  float w0 = e0*inv, w1 = e1*inv, w2 = e2*inv, w3 = e3*inv, w4 = e4*inv;
  if (l4 == 0){
    float* ap = outp + B_TOT + (size_t)rowA * 5;
    ap[0] = w0; ap[1] = w1; ap[2] = w2; ap[3] = w3; ap[4] = w4;
  }

  bf16x8 af[8];
  const u16* pr = proj + (size_t)rowA * 1280 + l4*8;
  #pragma unroll
  for (int kk = 0; kk < 8; kk++){
    u16x8 p0v = *(const u16x8*)(pr + kk*32);
    u16x8 p1v = *(const u16x8*)(pr + 256  + kk*32);
    u16x8 p2v = *(const u16x8*)(pr + 512  + kk*32);
    u16x8 p3v = *(const u16x8*)(pr + 768  + kk*32);
    u16x8 p4v = *(const u16x8*)(pr + 1024 + kk*32);
    bf16x8 a;
    #pragma unroll
    for (int j = 0; j < 8; j++)
      a[j] = (__bf16)(w0*bf2f(p0v[j]) + w1*bf2f(p1v[j]) + w2*bf2f(p2v[j])
                    + w3*bf2f(p3v[j]) + w4*bf2f(p4v[j]));
    af[kk] = a;
  }

  f32x4 acc1[8];
  #pragma unroll
  for (int of = 0; of < 8; of++) acc1[of] = f32x4{0.f,0.f,0.f,0.f};
  #pragma unroll
  for (int kk = 0; kk < 8; kk++){
    #pragma unroll
    for (int of = 0; of < 8; of++){
      bf16x8 b = *(const bf16x8*)((const char*)Wc1bf + (of*16 + l15)*512 + kk*64 + l4*16);
      acc1[of] = mfma16(af[kk], b, acc1[of]);
    }
  }
  float sum1[4] = {0.f,0.f,0.f,0.f};
  #pragma unroll
  for (int of = 0; of < 8; of++){
    float bb = bc1[of*16 + l15];
    #pragma unroll
    for (int rg = 0; rg < 4; rg++){ acc1[of][rg] += bb; sum1[rg] += acc1[of][rg]; }
  }
  #pragma unroll
  for (int rg = 0; rg < 4; rg++){
    #pragma unroll
    for (int d = 1; d < 16; d <<= 1) sum1[rg] += __shfl_xor(sum1[rg], d);
  }
  float vs1[4] = {0.f,0.f,0.f,0.f};
  float mean1[4];
  #pragma unroll
  for (int rg = 0; rg < 4; rg++) mean1[rg] = sum1[rg] * 0.0078125f;
  #pragma unroll
  for (int of = 0; of < 8; of++)
    #pragma unroll
    for (int rg = 0; rg < 4; rg++){ float dd = acc1[of][rg] - mean1[rg]; vs1[rg] += dd*dd; }
  #pragma unroll
  for (int rg = 0; rg < 4; rg++){
    #pragma unroll
    for (int d = 1; d < 16; d <<= 1) vs1[rg] += __shfl_xor(vs1[rg], d);
  }
  float is1[4];
  #pragma unroll
  for (int rg = 0; rg < 4; rg++) is1[rg] = rsqrtf(vs1[rg] * 0.0078125f + 1e-5f);
  #pragma unroll
  for (int of = 0; of < 8; of++){
    int col = of*16 + l15;
    float gg = g1[col], bb = be1[col];
    #pragma unroll
    for (int rg = 0; rg < 4; rg++){
      float h = fmaxf((acc1[of][rg] - mean1[rg]) * is1[rg] * gg + bb, 0.f);
      h1s[wv][(l4*4 + rg)*136 + col] = f2bf(h);
    }
  }

  f32x4 acc2[4];
  #pragma unroll
  for (int of = 0; of < 4; of++) acc2[of] = f32x4{0.f,0.f,0.f,0.f};
  #pragma unroll
  for (int kk = 0; kk < 4; kk++){
    bf16x8 a2 = *(const bf16x8*)((const char*)&h1s[wv][0] + l15*272 + kk*64 + l4*16);
    #pragma unroll
    for (int of = 0; of < 4; of++){
      bf16x8 b = *(const bf16x8*)((const char*)Wc2bf + (of*16 + l15)*256 + kk*64 + l4*16);
      acc2[of] = mfma16(a2, b, acc2[of]);
    }
  }
  float sum2[4] = {0.f,0.f,0.f,0.f};
  #pragma unroll
  for (int of = 0; of < 4; of++){
    float bb = bc2[of*16 + l15];
    #pragma unroll
    for (int rg = 0; rg < 4; rg++){ acc2[of][rg] += bb; sum2[rg] += acc2[of][rg]; }
  }
  #pragma unroll
  for (int rg = 0; rg < 4; rg++){
    #pragma unroll
    for (int d = 1; d < 16; d <<= 1) sum2[rg] += __shfl_xor(sum2[rg], d);
  }
  float mean2[4], vs2[4] = {0.f,0.f,0.f,0.f};
  #pragma unroll
  for (int rg = 0; rg < 4; rg++) mean2[rg] = sum2[rg] * 0.015625f;
  #pragma unroll
  for (int of = 0; of < 4; of++)
    #pragma unroll
    for (int rg = 0; rg < 4; rg++){ float dd = acc2[of][rg] - mean2[rg]; vs2[rg] += dd*dd; }
  #pragma unroll
  for (int rg = 0; rg < 4; rg++){
    #pragma unroll
    for (int d = 1; d < 16; d <<= 1) vs2[rg] += __shfl_xor(vs2[rg], d);
  }
  float po[4] = {0.f,0.f,0.f,0.f};
  #pragma unroll
  for (int of = 0; of < 4; of++){
    int col = of*16 + l15;
    float gg = g2[col], bb = be2[col], w3c = Wc3[col];
    #pragma unroll
    for (int rg = 0; rg < 4; rg++){
      float is2 = rsqrtf(vs2[rg] * 0.015625f + 1e-5f);
      float h = fmaxf((acc2[of][rg] - mean2[rg]) * is2 * gg + bb, 0.f);
      po[rg] += h * w3c;
    }
  }
  #pragma unroll
  for (int rg = 0; rg < 4; rg++){
    #pragma unroll
    for (int d = 1; d < 16; d <<= 1) po[rg] += __shfl_xor(po[rg], d);
  }
  if (l15 == 0){
    float b3 = bc3[0];
    #pragma unroll
    for (int rg = 0; rg < 4; rg++)
      outp[b0 + wv*16 + l4*4 + rg] = po[rg] + b3;
  }
}

extern "C" void kernel_launch(void* const* d_in, const int* in_sizes, int n_in,
                              void* d_out, int out_size, void* d_ws, size_t ws_size,
                              hipStream_t stream)
{
  (void)in_sizes; (void)n_in; (void)out_size; (void)ws_size;
  const float* ft1  = (const float*)d_in[0];
  const float* ft1c = (const float*)d_in[1];
  const float* ft2  = (const float*)d_in[2];
  const float* ftfl = (const float*)d_in[3];
  const float* fcl  = (const float*)d_in[4];
  const float* Wpmri= (const float*)d_in[5];
  const float* bpm  = (const float*)d_in[6];
  const float* Wpcl = (const float*)d_in[7];
  const float* bpcl = (const float*)d_in[8];
  const float* Wa1  = (const float*)d_in[9];
  const float* ba1  = (const float*)d_in[10];
  const float* Wa2  = (const float*)d_in[11];
  const float* ba2  = (const float*)d_in[12];
  const float* Wc1  = (const float*)d_in[13];
  const float* bc1  = (const float*)d_in[14];
  const float* g1   = (const float*)d_in[15];
  const float* be1  = (const float*)d_in[16];
  const float* Wc2  = (const float*)d_in[17];
  const float* bc2  = (const float*)d_in[18];
  const float* g2   = (const float*)d_in[19];
  const float* be2  = (const float*)d_in[20];
  const float* Wc3  = (const float*)d_in[21];
  const float* bc3  = (const float*)d_in[22];
  float* outp = (float*)d_out;
  char* ws = (char*)d_ws;

  u16*   proj   = (u16*)(ws);
  float* scores = (float*)(ws + WS_SCORES);
  u16*   Wpbf   = (u16*)(ws + WS_WP);
  u16*   Wa1bf  = (u16*)(ws + WS_WA1);
  u16*   Wc1bf  = (u16*)(ws + WS_WC1);
  u16*   Wc2bf  = (u16*)(ws + WS_WC2);

  (void)hipFuncSetAttribute((const void*)k1_proj, hipFuncAttributeMaxDynamicSharedMemorySize, 73728);

  k0_convert<<<dim3(512), dim3(256), 0, stream>>>(
      Wpmri, Wpbf, 4 * H_ * DM_,
      Wa1,  Wa1bf, 64 * H_,
      Wc1,  Wc1bf, 128 * H_,
      Wc2,  Wc2bf, 64 * 128);

  k1b_clin<<<dim3(256), dim3(256), 0, stream>>>(
      fcl, Wpcl, bpcl, Wa1bf, ba1, Wa2, ba2, proj, scores);

  k1_proj<<<dim3(1024), dim3(512), 73728, stream>>>(
      ft1, ft1c, ft2, ftfl, Wpbf, bpm, Wa1bf, ba1, Wa2, ba2, proj, scores);

  k2_cls<<<dim3(256), dim3(256), 0, stream>>>(
      proj, scores, Wc1bf, Wc2bf, bc1, g1, be1, bc2, g2, be2, Wc3, bc3, outp);
}